// Round 7
// baseline (180.389 us; speedup 1.0000x reference)
//
#include <hip/hip_runtime.h>

#define Bsz 64
#define Nn  256
#define Ee  20   // atom embedding dim
#define Dd  25   // gaussian centers
#define NBLK (Bsz * Nn / 4)   // 4096 blocks, 4 waves each, 1 wave per (b,i)

using short8  = __attribute__((ext_vector_type(8))) short;  // 8 bf16 (4 VGPRs)
using floatx4 = __attribute__((ext_vector_type(4))) float;  // 4 fp32 acc

#if __has_builtin(__builtin_amdgcn_exp2f)
#define EXP2F(x) __builtin_amdgcn_exp2f(x)
#else
#define EXP2F(x) __expf(0.6931471805599453f * (x))
#endif
#if __has_builtin(__builtin_amdgcn_rcpf)
#define RCPF(x) __builtin_amdgcn_rcpf(x)
#else
#define RCPF(x) (1.0f / (x))
#endif

__device__ __forceinline__ short f2bf(float x) {            // RNE fp32->bf16
    unsigned u = __float_as_uint(x);
    unsigned r = (u + 0x7FFFu + ((u >> 16) & 1u)) >> 16;
    return (short)r;
}
__device__ __forceinline__ float bf2f(short h) {
    return __uint_as_float(((unsigned)(unsigned short)h) << 16);
}
__device__ __forceinline__ float tanhfast(float x) {
    float e = __expf(2.0f * x);
    return 1.0f - 2.0f / (e + 1.0f);
}
// pack two fp32 -> two bf16 (RTNA; g-rounding uncorrelated, validated R6)
__device__ __forceinline__ unsigned packbf(float a, float b) {
#if __has_builtin(__builtin_amdgcn_perm)
    return __builtin_amdgcn_perm(__float_as_uint(b) + 0x8000u,
                                 __float_as_uint(a) + 0x8000u, 0x07060302u);
#else
    unsigned ua = (__float_as_uint(a) + 0x8000u) >> 16;
    unsigned ub = (__float_as_uint(b) + 0x8000u) & 0xFFFF0000u;
    return ua | ub;
#endif
}

// ---- workspace layout (bytes from d_ws base; all 16B-aligned) ----
#define WS_FRAGHI 0       // short[2*64*8]  = 2048 B
#define WS_FRAGLO 2048    // short[2*64*8]  = 2048 B
#define WS_ABK    4096    // float[256*20]  = 20480 B
#define WS_CF     24576   // float[256*20]  = 20480 B
#define WS_U      45056   // float[20]      = 80 B
#define WS_C0     45152   // float[1]
#define WS_PART   45184   // float[4096]    = 16384 B
#define WS_TICKET 61568   // unsigned[1]

// One-block setup: lane-native weight fragments, per-z bias/cfeat tables,
// folded top-MLP vector u and constant C0.
__global__ __launch_bounds__(256) void dtnn_setup(
    const float* __restrict__ Vw, const float* __restrict__ Vb,
    const float* __restrict__ emb,
    const float* __restrict__ W1, const float* __restrict__ b1,
    const float* __restrict__ W2, const float* __restrict__ b2,
    short* __restrict__ fragHi, short* __restrict__ fragLo,
    float* __restrict__ AbK, float* __restrict__ cfT,
    float* __restrict__ uT, float* __restrict__ C0out)
{
    const int tid = threadIdx.x;
    const float Kc = 2.8853900817779268f;   // 2*log2(e)

    if (tid < 64) {
        const int c16 = tid & 15, k0 = (tid >> 4) * 8;
        #pragma unroll
        for (int nt = 0; nt < 2; ++nt) {
            #pragma unroll
            for (int jj = 0; jj < 8; ++jj) {
                const int o = nt * 16 + c16, k = k0 + jj;
                float wvf = (o < Ee && k < Dd) ? Kc * Vw[o * 45 + 20 + k] : 0.0f;
                short h = f2bf(wvf);
                fragHi[(nt * 64 + tid) * 8 + jj] = h;
                fragLo[(nt * 64 + tid) * 8 + jj] = f2bf(wvf - bf2f(h));
            }
        }
    }
    if (tid < Ee) {
        float uo = 0.0f;
        #pragma unroll
        for (int p = 0; p < 10; ++p) uo = fmaf(W2[p], W1[p * Ee + tid], uo);
        uT[tid] = uo;
    }
    if (tid == 64) {
        float c0 = b2[0];
        #pragma unroll
        for (int p = 0; p < 10; ++p) c0 = fmaf(W2[p], b1[p], c0);
        C0out[0] = c0;
    }
    // per-z tables (depend only on the z VALUE)
    const int v = tid;
    const float m = (v != 0) ? 1.0f : 0.0f;
    for (int o = 0; o < Ee; ++o) {
        float dot = 0.0f;
        #pragma unroll
        for (int f = 0; f < Ee; ++f)
            dot = fmaf(Vw[o * 45 + f], emb[v * Ee + f], dot);
        AbK[v * Ee + o] = Kc * (Vb[o] + m * dot);
        cfT[v * Ee + o] = m * emb[v * Ee + o];
    }
}

__global__ __launch_bounds__(256) void dtnn_kernel(
    const int*   __restrict__ z,      // [B,N]
    const float* __restrict__ dist,   // [B,N,N]
    const short* __restrict__ fragHi, // [2][64][8] lane-native
    const short* __restrict__ fragLo,
    const float* __restrict__ AbK,    // [256][20] by z-value
    const float* __restrict__ cfT,    // [256][20]
    const float* __restrict__ uT,     // [20]
    const float* __restrict__ C0p,    // [1]
    float*       __restrict__ part,   // [NBLK]
    unsigned*    __restrict__ ticket, // [1] (poisoned base 0 or 0xAAAAAAAA)
    float*       __restrict__ out)    // [B]
{
    const int tid  = threadIdx.x;
    const int lane = tid & 63;
    const int wave = tid >> 6;
    const int wv   = blockIdx.x * 4 + wave;  // global (b,i); 4 waves share b
    const int b    = wv >> 8;
    const int i    = wv & 255;

    const int c16  = lane & 15;
    const int quad = lane >> 4;
    const int k0   = quad * 8;

    // dist row up-front: 4 coalesced b32 loads, lane l holds d[l + 64c]
    const float* drow = dist + (size_t)(b * Nn + i) * Nn;
    const float d0 = drow[lane];
    const float d1 = drow[lane + 64];
    const float d2 = drow[lane + 128];
    const float d3 = drow[lane + 192];

    // weight fragments: coalesced b128 loads in lane layout
    const short8* fH = (const short8*)fragHi;
    const short8* fL = (const short8*)fragLo;
    short8 whiK[2], wloK[2];
    whiK[0] = fH[lane];       whiK[1] = fH[64 + lane];
    wloK[0] = fL[lane];       wloK[1] = fL[64 + lane];

    const int   zi    = z[b * Nn + i];         // wave-uniform
    const float maskv = (zi != 0) ? 1.0f : 0.0f;

    float AbKv[2], cfo[2];
    #pragma unroll
    for (int nt = 0; nt < 2; ++nt) {
        const int o = nt * 16 + c16;
        AbKv[nt] = (o < Ee) ? AbK[zi * Ee + o] : 0.0f;
        cfo[nt]  = (o < Ee) ? cfT[zi * Ee + o] : 0.0f;
    }
    const floatx4 bias0 = {AbKv[0], AbKv[0], AbKv[0], AbKv[0]};
    const floatx4 bias1 = {AbKv[1], AbKv[1], AbKv[1], AbKv[1]};

    // ---- main loop: 16 j-tiles; tanh-sum as  sum tanh = 256 - 2*sum sigma
    const float mu0 = 0.2f * (float)k0;
    const float CR  = 0.8521437889662113f;   // exp(-0.16)

    float R0 = 0.0f, R1 = 0.0f;

    #pragma unroll 4
    for (int t = 0; t < 16; ++t) {
        // d for my row j = t*16 + c16 via register bpermute (no global load)
        const int srcLane = 16 * (t & 3) + c16;
        float s01 = (t & 4) ? d1 : d0;
        float s23 = (t & 4) ? d3 : d2;
        float dv  = (t & 8) ? s23 : s01;
        const float d = __shfl(dv, srcLane, 64);

        // RBF recurrence in exp2 domain: g=exp(-2u^2), r=exp(0.8u-0.08)
        const float u = d - mu0;
        float g = EXP2F(-2.8853900817779268f * (u * u));
        float r = EXP2F(fmaf(1.1541560327111707f, u, -0.11541560327111707f));
        float gv[8];
        gv[0] = g;
        #pragma unroll
        for (int jj = 1; jj < 8; ++jj) { g *= r; r *= CR; gv[jj] = g; }
        union { short8 s; unsigned u4[4]; } G;
        #pragma unroll
        for (int q = 0; q < 4; ++q) G.u4[q] = packbf(gv[2 * q], gv[2 * q + 1]);
        const short8 ghi = G.s;

        // first MFMA consumes loop-invariant bias as C (no acc-init movs)
        floatx4 acc0 = __builtin_amdgcn_mfma_f32_16x16x32_bf16(ghi, whiK[0], bias0, 0, 0, 0);
        acc0 = __builtin_amdgcn_mfma_f32_16x16x32_bf16(ghi, wloK[0], acc0, 0, 0, 0);
        floatx4 acc1 = __builtin_amdgcn_mfma_f32_16x16x32_bf16(ghi, whiK[1], bias1, 0, 0, 0);
        acc1 = __builtin_amdgcn_mfma_f32_16x16x32_bf16(ghi, wloK[1], acc1, 0, 0, 0);

        // sigma-sum with 4-way reciprocal combine: 1 rcp per 4 sigmas.
        // A_i = 2^{acc_i} + 1 >= 1 (no overflow: |acc| <~ 5 at this data scale)
        {
            const float A0 = EXP2F(acc0[0]) + 1.0f;
            const float A1 = EXP2F(acc0[1]) + 1.0f;
            const float A2 = EXP2F(acc0[2]) + 1.0f;
            const float A3 = EXP2F(acc0[3]) + 1.0f;
            const float p01 = A0 * A1, p23 = A2 * A3;
            const float s01a = A0 + A1, s23a = A2 + A3;
            const float num = fmaf(p01, s23a, p23 * s01a);
            const float rd  = RCPF(p01 * p23);
            R0 = fmaf(num, rd, R0);
        }
        {
            const float A0 = EXP2F(acc1[0]) + 1.0f;
            const float A1 = EXP2F(acc1[1]) + 1.0f;
            const float A2 = EXP2F(acc1[2]) + 1.0f;
            const float A3 = EXP2F(acc1[3]) + 1.0f;
            const float p01 = A0 * A1, p23 = A2 * A3;
            const float s01a = A0 + A1, s23a = A2 + A3;
            const float num = fmaf(p01, s23a, p23 * s01a);
            const float rd  = RCPF(p01 * p23);
            R1 = fmaf(num, rd, R1);
        }
    }

    // reduce sigma-sums over quads
    R0 += __shfl_xor(R0, 16, 64);
    R0 += __shfl_xor(R0, 32, 64);
    R1 += __shfl_xor(R1, 16, 64);
    R1 += __shfl_xor(R1, 32, 64);
    const float agg0 = 256.0f - 2.0f * R0;
    const float agg1 = 256.0f - 2.0f * R1;

    // epilogue: th = tanh(cfeat + mask*agg); e = sum_o u[o]*th[o]
    float e = 0.0f;
    #pragma unroll
    for (int nt = 0; nt < 2; ++nt) {
        const int o   = nt * 16 + c16;
        const float agg = (nt == 0) ? agg0 : agg1;
        const float th  = tanhfast(cfo[nt] + maskv * agg);
        const float uo  = (o < Ee) ? uT[o] : 0.0f;
        e = fmaf(th, uo, e);
    }
    e += __shfl_xor(e, 1, 64);
    e += __shfl_xor(e, 2, 64);
    e += __shfl_xor(e, 4, 64);
    e += __shfl_xor(e, 8, 64);

    // block reduce: 4 waves -> one partial, then last-block-done final sum
    __shared__ float sE[4];
    __shared__ float sRed[256];
    __shared__ int   sLast;
    if (lane == 0) sE[wave] = e;
    __syncthreads();
    if (tid == 0) {
        part[blockIdx.x] = sE[0] + sE[1] + sE[2] + sE[3];
        __threadfence();                          // release: partial visible
        const unsigned old = atomicAdd(ticket, 1u);
        const unsigned fin = old - (unsigned)(NBLK - 1);
        // baseline-free: ws poisoned 0xAA (timed) or 0 (fresh) both detected
        sLast = (fin == 0u || fin == 0xAAAAAAAAu) ? 1 : 0;
    }
    __syncthreads();

    if (sLast) {
        __threadfence();                          // acquire: see all partials
        float s = 0.0f;
        const int base = tid * 16;                // blocks [tid*16, tid*16+15]
        #pragma unroll
        for (int k = 0; k < 16; ++k) s += part[base + k];
        sRed[tid] = s;
        __syncthreads();
        if (tid < Bsz)
            out[tid] = sRed[4 * tid] + sRed[4 * tid + 1] +
                       sRed[4 * tid + 2] + sRed[4 * tid + 3] + 256.0f * C0p[0];
    }
}

extern "C" void kernel_launch(void* const* d_in, const int* in_sizes, int n_in,
                              void* d_out, int out_size, void* d_ws, size_t ws_size,
                              hipStream_t stream) {
    const int*   z    = (const int*)  d_in[0];
    const float* dist = (const float*)d_in[1];
    const float* emb  = (const float*)d_in[2];
    const float* Vw   = (const float*)d_in[3];
    const float* Vb   = (const float*)d_in[4];
    const float* W1   = (const float*)d_in[5];
    const float* b1   = (const float*)d_in[6];
    const float* W2   = (const float*)d_in[7];
    const float* b2   = (const float*)d_in[8];
    float* out = (float*)d_out;

    char* ws = (char*)d_ws;
    short*    fragHi = (short*)(ws + WS_FRAGHI);
    short*    fragLo = (short*)(ws + WS_FRAGLO);
    float*    AbK    = (float*)(ws + WS_ABK);
    float*    cfT    = (float*)(ws + WS_CF);
    float*    uT     = (float*)(ws + WS_U);
    float*    C0p    = (float*)(ws + WS_C0);
    float*    partP  = (float*)(ws + WS_PART);
    unsigned* ticket = (unsigned*)(ws + WS_TICKET);

    dtnn_setup<<<1, 256, 0, stream>>>(Vw, Vb, emb, W1, b1, W2, b2,
                                      fragHi, fragLo, AbK, cfT, uT, C0p);

    // one wave per (b,i): B*N = 16384 waves, 4 waves/block -> 4096 blocks.
    // Final reduction fused via last-block-done ticket (no third dispatch).
    dtnn_kernel<<<NBLK, 256, 0, stream>>>(
        z, dist, fragHi, fragLo, AbK, cfT, uT, C0p, partP, ticket, out);
}

// Round 8
// 126.919 us; speedup vs baseline: 1.4213x; 1.4213x over previous
//
#include <hip/hip_runtime.h>

#define Bsz 64
#define Nn  256
#define Ee  20   // atom embedding dim
#define Dd  25   // gaussian centers
#define NBLK (Bsz * Nn / 4)   // 4096 blocks, 4 waves each, 1 wave per (b,i)

using short8  = __attribute__((ext_vector_type(8))) short;  // 8 bf16 (4 VGPRs)
using floatx4 = __attribute__((ext_vector_type(4))) float;  // 4 fp32 acc

#if __has_builtin(__builtin_amdgcn_exp2f)
#define EXP2F(x) __builtin_amdgcn_exp2f(x)
#else
#define EXP2F(x) __expf(0.6931471805599453f * (x))
#endif
#if __has_builtin(__builtin_amdgcn_rcpf)
#define RCPF(x) __builtin_amdgcn_rcpf(x)
#else
#define RCPF(x) (1.0f / (x))
#endif

__device__ __forceinline__ short f2bf(float x) {            // RNE fp32->bf16
    unsigned u = __float_as_uint(x);
    unsigned r = (u + 0x7FFFu + ((u >> 16) & 1u)) >> 16;
    return (short)r;
}
__device__ __forceinline__ float bf2f(short h) {
    return __uint_as_float(((unsigned)(unsigned short)h) << 16);
}
__device__ __forceinline__ float tanhfast(float x) {
    float e = __expf(2.0f * x);
    return 1.0f - 2.0f / (e + 1.0f);
}
// pack two fp32 -> two bf16 (RTNA; g-rounding uncorrelated, validated R6/R7)
__device__ __forceinline__ unsigned packbf(float a, float b) {
#if __has_builtin(__builtin_amdgcn_perm)
    return __builtin_amdgcn_perm(__float_as_uint(b) + 0x8000u,
                                 __float_as_uint(a) + 0x8000u, 0x07060302u);
#else
    unsigned ua = (__float_as_uint(a) + 0x8000u) >> 16;
    unsigned ub = (__float_as_uint(b) + 0x8000u) & 0xFFFF0000u;
    return ua | ub;
#endif
}

// ---- workspace layout (bytes from d_ws base; all 16B-aligned) ----
#define WS_FRAGHI 0       // short[2*64*8]  = 2048 B
#define WS_FRAGLO 2048    // short[2*64*8]  = 2048 B
#define WS_ABK    4096    // float[256*20]  = 20480 B
#define WS_CF     24576   // float[256*20]  = 20480 B
#define WS_U      45056   // float[20]      = 80 B
#define WS_C0     45152   // float[1]
#define WS_PART   45184   // float[4096]    = 16384 B
// total 61568 B

// One-block setup: lane-native weight fragments, per-z bias/cfeat tables,
// folded top-MLP vector u and constant C0.
__global__ __launch_bounds__(256) void dtnn_setup(
    const float* __restrict__ Vw, const float* __restrict__ Vb,
    const float* __restrict__ emb,
    const float* __restrict__ W1, const float* __restrict__ b1,
    const float* __restrict__ W2, const float* __restrict__ b2,
    short* __restrict__ fragHi, short* __restrict__ fragLo,
    float* __restrict__ AbK, float* __restrict__ cfT,
    float* __restrict__ uT, float* __restrict__ C0out)
{
    const int tid = threadIdx.x;
    const float Kc = 2.8853900817779268f;   // 2*log2(e)

    if (tid < 64) {
        const int c16 = tid & 15, k0 = (tid >> 4) * 8;
        #pragma unroll
        for (int nt = 0; nt < 2; ++nt) {
            #pragma unroll
            for (int jj = 0; jj < 8; ++jj) {
                const int o = nt * 16 + c16, k = k0 + jj;
                float wvf = (o < Ee && k < Dd) ? Kc * Vw[o * 45 + 20 + k] : 0.0f;
                short h = f2bf(wvf);
                fragHi[(nt * 64 + tid) * 8 + jj] = h;
                fragLo[(nt * 64 + tid) * 8 + jj] = f2bf(wvf - bf2f(h));
            }
        }
    }
    if (tid < Ee) {
        float uo = 0.0f;
        #pragma unroll
        for (int p = 0; p < 10; ++p) uo = fmaf(W2[p], W1[p * Ee + tid], uo);
        uT[tid] = uo;
    }
    if (tid == 64) {
        float c0 = b2[0];
        #pragma unroll
        for (int p = 0; p < 10; ++p) c0 = fmaf(W2[p], b1[p], c0);
        C0out[0] = c0;
    }
    // per-z tables (depend only on the z VALUE)
    const int v = tid;
    const float m = (v != 0) ? 1.0f : 0.0f;
    for (int o = 0; o < Ee; ++o) {
        float dot = 0.0f;
        #pragma unroll
        for (int f = 0; f < Ee; ++f)
            dot = fmaf(Vw[o * 45 + f], emb[v * Ee + f], dot);
        AbK[v * Ee + o] = Kc * (Vb[o] + m * dot);
        cfT[v * Ee + o] = m * emb[v * Ee + o];
    }
}

__global__ __launch_bounds__(256) void dtnn_kernel(
    const int*   __restrict__ z,      // [B,N]
    const float* __restrict__ dist,   // [B,N,N]
    const short* __restrict__ fragHi, // [2][64][8] lane-native
    const short* __restrict__ fragLo,
    const float* __restrict__ AbK,    // [256][20] by z-value
    const float* __restrict__ cfT,    // [256][20]
    const float* __restrict__ uT,     // [20]
    float*       __restrict__ part)   // [NBLK] per-block partials
{
    const int tid  = threadIdx.x;
    const int lane = tid & 63;
    const int wave = tid >> 6;
    const int wv   = blockIdx.x * 4 + wave;  // global (b,i); 4 waves share b
    const int b    = wv >> 8;
    const int i    = wv & 255;

    const int c16  = lane & 15;
    const int quad = lane >> 4;
    const int k0   = quad * 8;

    // dist row up-front: 4 coalesced b32 loads, lane l holds d[l + 64c]
    const float* drow = dist + (size_t)(b * Nn + i) * Nn;
    const float d0 = drow[lane];
    const float d1 = drow[lane + 64];
    const float d2 = drow[lane + 128];
    const float d3 = drow[lane + 192];

    // weight fragments: coalesced b128 loads in lane layout
    const short8* fH = (const short8*)fragHi;
    const short8* fL = (const short8*)fragLo;
    short8 whiK[2], wloK[2];
    whiK[0] = fH[lane];       whiK[1] = fH[64 + lane];
    wloK[0] = fL[lane];       wloK[1] = fL[64 + lane];

    const int   zi    = z[b * Nn + i];         // wave-uniform
    const float maskv = (zi != 0) ? 1.0f : 0.0f;

    float AbKv[2], cfo[2];
    #pragma unroll
    for (int nt = 0; nt < 2; ++nt) {
        const int o = nt * 16 + c16;
        AbKv[nt] = (o < Ee) ? AbK[zi * Ee + o] : 0.0f;
        cfo[nt]  = (o < Ee) ? cfT[zi * Ee + o] : 0.0f;
    }
    const floatx4 bias0 = {AbKv[0], AbKv[0], AbKv[0], AbKv[0]};
    const floatx4 bias1 = {AbKv[1], AbKv[1], AbKv[1], AbKv[1]};

    // ---- main loop: 16 j-tiles; tanh-sum as  sum tanh = 256 - 2*sum sigma
    const float mu0 = 0.2f * (float)k0;
    const float CR  = 0.8521437889662113f;   // exp(-0.16)

    float R0 = 0.0f, R1 = 0.0f;

    #pragma unroll 4
    for (int t = 0; t < 16; ++t) {
        // d for my row j = t*16 + c16 via register bpermute (no global load)
        const int srcLane = 16 * (t & 3) + c16;
        float s01 = (t & 4) ? d1 : d0;
        float s23 = (t & 4) ? d3 : d2;
        float dv  = (t & 8) ? s23 : s01;
        const float d = __shfl(dv, srcLane, 64);

        // RBF recurrence in exp2 domain: g=exp(-2u^2), r=exp(0.8u-0.08)
        const float u = d - mu0;
        float g = EXP2F(-2.8853900817779268f * (u * u));
        float r = EXP2F(fmaf(1.1541560327111707f, u, -0.11541560327111707f));
        float gv[8];
        gv[0] = g;
        #pragma unroll
        for (int jj = 1; jj < 8; ++jj) { g *= r; r *= CR; gv[jj] = g; }
        union { short8 s; unsigned u4[4]; } G;
        #pragma unroll
        for (int q = 0; q < 4; ++q) G.u4[q] = packbf(gv[2 * q], gv[2 * q + 1]);
        const short8 ghi = G.s;

        // first MFMA consumes loop-invariant bias as C (no acc-init movs)
        floatx4 acc0 = __builtin_amdgcn_mfma_f32_16x16x32_bf16(ghi, whiK[0], bias0, 0, 0, 0);
        acc0 = __builtin_amdgcn_mfma_f32_16x16x32_bf16(ghi, wloK[0], acc0, 0, 0, 0);
        floatx4 acc1 = __builtin_amdgcn_mfma_f32_16x16x32_bf16(ghi, whiK[1], bias1, 0, 0, 0);
        acc1 = __builtin_amdgcn_mfma_f32_16x16x32_bf16(ghi, wloK[1], acc1, 0, 0, 0);

        // sigma-sum with 4-way reciprocal combine: 1 rcp per 4 sigmas.
        // A_i = 2^{acc_i} + 1 >= 1 (no overflow: |acc| <~ 5 at this data scale)
        {
            const float A0 = EXP2F(acc0[0]) + 1.0f;
            const float A1 = EXP2F(acc0[1]) + 1.0f;
            const float A2 = EXP2F(acc0[2]) + 1.0f;
            const float A3 = EXP2F(acc0[3]) + 1.0f;
            const float p01 = A0 * A1, p23 = A2 * A3;
            const float num = fmaf(p01, A2 + A3, p23 * (A0 + A1));
            R0 = fmaf(num, RCPF(p01 * p23), R0);
        }
        {
            const float A0 = EXP2F(acc1[0]) + 1.0f;
            const float A1 = EXP2F(acc1[1]) + 1.0f;
            const float A2 = EXP2F(acc1[2]) + 1.0f;
            const float A3 = EXP2F(acc1[3]) + 1.0f;
            const float p01 = A0 * A1, p23 = A2 * A3;
            const float num = fmaf(p01, A2 + A3, p23 * (A0 + A1));
            R1 = fmaf(num, RCPF(p01 * p23), R1);
        }
    }

    // reduce sigma-sums over quads
    R0 += __shfl_xor(R0, 16, 64);
    R0 += __shfl_xor(R0, 32, 64);
    R1 += __shfl_xor(R1, 16, 64);
    R1 += __shfl_xor(R1, 32, 64);
    const float agg0 = 256.0f - 2.0f * R0;
    const float agg1 = 256.0f - 2.0f * R1;

    // epilogue: th = tanh(cfeat + mask*agg); e = sum_o u[o]*th[o]
    float e = 0.0f;
    #pragma unroll
    for (int nt = 0; nt < 2; ++nt) {
        const int o   = nt * 16 + c16;
        const float agg = (nt == 0) ? agg0 : agg1;
        const float th  = tanhfast(cfo[nt] + maskv * agg);
        const float uo  = (o < Ee) ? uT[o] : 0.0f;
        e = fmaf(th, uo, e);
    }
    e += __shfl_xor(e, 1, 64);
    e += __shfl_xor(e, 2, 64);
    e += __shfl_xor(e, 4, 64);
    e += __shfl_xor(e, 8, 64);

    // block-level reduce: 4 waves -> one plain store (NO atomics anywhere)
    __shared__ float sE[4];
    if (lane == 0) sE[wave] = e;
    __syncthreads();
    if (tid == 0)
        part[blockIdx.x] = sE[0] + sE[1] + sE[2] + sE[3];
}

// 64 blocks x 64 lanes: out[b] = sum of 64 block-partials + 256*C0
__global__ __launch_bounds__(64) void dtnn_reduce(
    const float* __restrict__ part, const float* __restrict__ C0p,
    float* __restrict__ out)
{
    const int b = blockIdx.x;
    const int t = threadIdx.x;
    float v = part[b * 64 + t];
    v += __shfl_xor(v, 1, 64);
    v += __shfl_xor(v, 2, 64);
    v += __shfl_xor(v, 4, 64);
    v += __shfl_xor(v, 8, 64);
    v += __shfl_xor(v, 16, 64);
    v += __shfl_xor(v, 32, 64);
    if (t == 0) out[b] = v + 256.0f * C0p[0];
}

extern "C" void kernel_launch(void* const* d_in, const int* in_sizes, int n_in,
                              void* d_out, int out_size, void* d_ws, size_t ws_size,
                              hipStream_t stream) {
    const int*   z    = (const int*)  d_in[0];
    const float* dist = (const float*)d_in[1];
    const float* emb  = (const float*)d_in[2];
    const float* Vw   = (const float*)d_in[3];
    const float* Vb   = (const float*)d_in[4];
    const float* W1   = (const float*)d_in[5];
    const float* b1   = (const float*)d_in[6];
    const float* W2   = (const float*)d_in[7];
    const float* b2   = (const float*)d_in[8];
    float* out = (float*)d_out;

    char* ws = (char*)d_ws;
    short* fragHi = (short*)(ws + WS_FRAGHI);
    short* fragLo = (short*)(ws + WS_FRAGLO);
    float* AbK    = (float*)(ws + WS_ABK);
    float* cfT    = (float*)(ws + WS_CF);
    float* uT     = (float*)(ws + WS_U);
    float* C0p    = (float*)(ws + WS_C0);
    float* partP  = (float*)(ws + WS_PART);

    dtnn_setup<<<1, 256, 0, stream>>>(Vw, Vb, emb, W1, b1, W2, b2,
                                      fragHi, fragLo, AbK, cfT, uT, C0p);

    // one wave per (b,i): B*N = 16384 waves, 4 waves/block -> 4096 blocks
    dtnn_kernel<<<NBLK, 256, 0, stream>>>(
        z, dist, fragHi, fragLo, AbK, cfT, uT, partP);

    // final: 64 partial-sums per batch -> out[b] (fully overwrites d_out)
    dtnn_reduce<<<Bsz, 64, 0, stream>>>(partP, C0p, out);
}

// Round 9
// 121.831 us; speedup vs baseline: 1.4806x; 1.0418x over previous
//
#include <hip/hip_runtime.h>

#define Bsz 64
#define Nn  256
#define Ee  20   // atom embedding dim
#define Dd  25   // gaussian centers
#define NBLK 2048  // 2048 blocks x 4 waves x 2 rows = 16384 (b,i) rows

using short8  = __attribute__((ext_vector_type(8))) short;  // 8 bf16 (4 VGPRs)
using floatx4 = __attribute__((ext_vector_type(4))) float;  // 4 fp32 acc

#if __has_builtin(__builtin_amdgcn_exp2f)
#define EXP2F(x) __builtin_amdgcn_exp2f(x)
#else
#define EXP2F(x) __expf(0.6931471805599453f * (x))
#endif
#if __has_builtin(__builtin_amdgcn_rcpf)
#define RCPF(x) __builtin_amdgcn_rcpf(x)
#else
#define RCPF(x) (1.0f / (x))
#endif

__device__ __forceinline__ short f2bf(float x) {            // RNE fp32->bf16
    unsigned u = __float_as_uint(x);
    unsigned r = (u + 0x7FFFu + ((u >> 16) & 1u)) >> 16;
    return (short)r;
}
__device__ __forceinline__ float bf2f(short h) {
    return __uint_as_float(((unsigned)(unsigned short)h) << 16);
}
__device__ __forceinline__ float tanhfast(float x) {
    float e = __expf(2.0f * x);
    return 1.0f - 2.0f / (e + 1.0f);
}
// pack two fp32 -> two bf16 (RTNA; validated R6-R8)
__device__ __forceinline__ unsigned packbf(float a, float b) {
#if __has_builtin(__builtin_amdgcn_perm)
    return __builtin_amdgcn_perm(__float_as_uint(b) + 0x8000u,
                                 __float_as_uint(a) + 0x8000u, 0x07060302u);
#else
    unsigned ua = (__float_as_uint(a) + 0x8000u) >> 16;
    unsigned ub = (__float_as_uint(b) + 0x8000u) & 0xFFFF0000u;
    return ua | ub;
#endif
}

// Main kernel: self-sufficient (no setup dispatch). Each wave owns 2 rows
// (b, i0) and (b, i0+1); 4 waves/block share b. Per-block partial -> part[].
__global__ __launch_bounds__(256, 4) void dtnn_main(
    const int*   __restrict__ z,     // [B,N]
    const float* __restrict__ dist,  // [B,N,N]
    const float* __restrict__ emb,   // [N,E]
    const float* __restrict__ Vw,    // [E,45]
    const float* __restrict__ Vb,    // [E]
    const float* __restrict__ W1,    // [10,E]
    const float* __restrict__ W2,    // [1,10]
    float*       __restrict__ part)  // [NBLK]
{
    const int tid  = threadIdx.x;
    const int lane = tid & 63;
    const int wave = tid >> 6;
    const int blk  = blockIdx.x;
    const int b    = blk >> 5;                       // 32 blocks per batch
    const int i0   = ((blk & 31) << 3) | (wave << 1);// rows i0, i0+1

    const int c16  = lane & 15;
    const int quad = lane >> 4;
    const int k0   = quad * 8;
    const float Kc = 2.8853900817779268f;            // 2*log2(e)
    const float T04 = 1.1541560327111707f;           // 0.4*Kc

    // dist rows up-front (8 coalesced b32 loads; issue before prologue ALU)
    const float* dr0 = dist + ((size_t)b * Nn + i0) * Nn;
    const float a0r = dr0[lane],        a1r = dr0[lane + 64];
    const float a2r = dr0[lane + 128],  a3r = dr0[lane + 192];
    const float b0r = dr0[Nn + lane],       b1r = dr0[Nn + lane + 64];
    const float b2r = dr0[Nn + lane + 128], b3r = dr0[Nn + lane + 192];

    const int zi0 = z[b * Nn + i0];
    const int zi1 = z[b * Nn + i0 + 1];
    const int zu0 = __builtin_amdgcn_readfirstlane(zi0);  // wave-uniform
    const int zu1 = __builtin_amdgcn_readfirstlane(zi1);
    const float m0 = (zu0 != 0) ? 1.0f : 0.0f;
    const float m1 = (zu1 != 0) ? 1.0f : 0.0f;

    // Gaussian step constants c_jj = e^{-0.08 jj^2}, folded into the weights:
    // g_{k0+jj} = g0 * t^jj * c_jj, t = e^{0.8u}  (shallow power tree in-loop)
    const float cj[8] = {1.0f, 0.9231163463866358f, 0.7261490370736909f,
                         0.48675225595997157f, 0.2780373004531941f,
                         0.1353352832366127f, 0.05613476283303940f,
                         0.019841459768337877f};

    // weight fragments (divergent gathers; L1-hot after first blocks - R4/R5
    // evidence showed these are cheap) + per-row bias/cfeat
    short8 whiK[2], wloK[2];
    floatx4 bias0[2], bias1[2];
    float cf0[2], cf1[2];
    #pragma unroll
    for (int nt = 0; nt < 2; ++nt) {
        const int o = nt * 16 + c16;
        const bool valid = (o < Ee);
        const int oc = valid ? o : 0;                 // clamp vs OOB speculation
        #pragma unroll
        for (int jj = 0; jj < 8; ++jj) {
            const int k = k0 + jj;
            const float v = (valid && k < Dd)
                          ? Kc * cj[jj] * Vw[oc * 45 + 20 + k] : 0.0f;
            const short h = f2bf(v);
            whiK[nt][jj] = h;
            wloK[nt][jj] = f2bf(v - bf2f(h));
        }
        // A[o] = Kc*(Vb[o] + m * Vw[o,:20].emb[z]) ; cfeat = m*emb[z][o]
        float dot0 = 0.0f, dot1 = 0.0f;
        #pragma unroll
        for (int f = 0; f < Ee; ++f) {
            const float w = valid ? Vw[oc * 45 + f] : 0.0f;
            dot0 = fmaf(w, emb[zu0 * Ee + f], dot0);   // emb: s_loads (uniform)
            dot1 = fmaf(w, emb[zu1 * Ee + f], dot1);
        }
        const float vb = valid ? Vb[oc] : 0.0f;
        const float A0 = Kc * (vb + m0 * dot0);
        const float A1 = Kc * (vb + m1 * dot1);
        bias0[nt] = (floatx4){A0, A0, A0, A0};
        bias1[nt] = (floatx4){A1, A1, A1, A1};
        cf0[nt] = valid ? m0 * emb[zu0 * Ee + oc] : 0.0f;
        cf1[nt] = valid ? m1 * emb[zu1 * Ee + oc] : 0.0f;
    }

    // ---- main loop: 16 j-tiles x 2 rows; sum tanh = 256 - 2*sum sigma
    const float mu0 = 0.2f * (float)k0;
    float R00 = 0.0f, R01 = 0.0f, R10 = 0.0f, R11 = 0.0f;

    #pragma unroll 2
    for (int t = 0; t < 16; ++t) {
        const int srcLane = 16 * (t & 3) + c16;
        // row 0 d
        float s01 = (t & 4) ? a1r : a0r;
        float s23 = (t & 4) ? a3r : a2r;
        const float dv0 = (t & 8) ? s23 : s01;
        const float d0 = __shfl(dv0, srcLane, 64);
        // row 1 d
        float u01 = (t & 4) ? b1r : b0r;
        float u23 = (t & 4) ? b3r : b2r;
        const float dv1 = (t & 8) ? u23 : u01;
        const float d1 = __shfl(dv1, srcLane, 64);

        // row 0: a_jj = g0 * t^jj (c_jj folded into weights)
        short8 gA, gB;
        {
            const float u = d0 - mu0;
            const float g0 = EXP2F((-Kc * u) * u);
            const float tp = EXP2F(T04 * u);
            const float t2 = tp * tp, t3 = t2 * tp, t4 = t2 * t2;
            const float x1 = g0 * tp, x2 = g0 * t2, x3 = g0 * t3, x4 = g0 * t4;
            union { short8 s; unsigned u4[4]; } G;
            G.u4[0] = packbf(g0, x1);
            G.u4[1] = packbf(x2, x3);
            G.u4[2] = packbf(x4, x1 * t4);
            G.u4[3] = packbf(x2 * t4, x3 * t4);
            gA = G.s;
        }
        // row 1
        {
            const float u = d1 - mu0;
            const float g0 = EXP2F((-Kc * u) * u);
            const float tp = EXP2F(T04 * u);
            const float t2 = tp * tp, t3 = t2 * tp, t4 = t2 * t2;
            const float x1 = g0 * tp, x2 = g0 * t2, x3 = g0 * t3, x4 = g0 * t4;
            union { short8 s; unsigned u4[4]; } G;
            G.u4[0] = packbf(g0, x1);
            G.u4[1] = packbf(x2, x3);
            G.u4[2] = packbf(x4, x1 * t4);
            G.u4[3] = packbf(x2 * t4, x3 * t4);
            gB = G.s;
        }

        // 8 MFMAs (2 rows x 2 ntiles x hi/lo), bias as C operand
        floatx4 p00 = __builtin_amdgcn_mfma_f32_16x16x32_bf16(gA, whiK[0], bias0[0], 0, 0, 0);
        p00 = __builtin_amdgcn_mfma_f32_16x16x32_bf16(gA, wloK[0], p00, 0, 0, 0);
        floatx4 p01 = __builtin_amdgcn_mfma_f32_16x16x32_bf16(gA, whiK[1], bias0[1], 0, 0, 0);
        p01 = __builtin_amdgcn_mfma_f32_16x16x32_bf16(gA, wloK[1], p01, 0, 0, 0);
        floatx4 p10 = __builtin_amdgcn_mfma_f32_16x16x32_bf16(gB, whiK[0], bias1[0], 0, 0, 0);
        p10 = __builtin_amdgcn_mfma_f32_16x16x32_bf16(gB, wloK[0], p10, 0, 0, 0);
        floatx4 p11 = __builtin_amdgcn_mfma_f32_16x16x32_bf16(gB, whiK[1], bias1[1], 0, 0, 0);
        p11 = __builtin_amdgcn_mfma_f32_16x16x32_bf16(gB, wloK[1], p11, 0, 0, 0);

        // sigma sums, 4-way reciprocal combine (1 rcp / 4 sigmas)
        {
            const float A0 = EXP2F(p00[0]) + 1.0f, A1 = EXP2F(p00[1]) + 1.0f;
            const float A2 = EXP2F(p00[2]) + 1.0f, A3 = EXP2F(p00[3]) + 1.0f;
            const float q01 = A0 * A1, q23 = A2 * A3;
            R00 = fmaf(fmaf(q01, A2 + A3, q23 * (A0 + A1)), RCPF(q01 * q23), R00);
        }
        {
            const float A0 = EXP2F(p01[0]) + 1.0f, A1 = EXP2F(p01[1]) + 1.0f;
            const float A2 = EXP2F(p01[2]) + 1.0f, A3 = EXP2F(p01[3]) + 1.0f;
            const float q01 = A0 * A1, q23 = A2 * A3;
            R01 = fmaf(fmaf(q01, A2 + A3, q23 * (A0 + A1)), RCPF(q01 * q23), R01);
        }
        {
            const float A0 = EXP2F(p10[0]) + 1.0f, A1 = EXP2F(p10[1]) + 1.0f;
            const float A2 = EXP2F(p10[2]) + 1.0f, A3 = EXP2F(p10[3]) + 1.0f;
            const float q01 = A0 * A1, q23 = A2 * A3;
            R10 = fmaf(fmaf(q01, A2 + A3, q23 * (A0 + A1)), RCPF(q01 * q23), R10);
        }
        {
            const float A0 = EXP2F(p11[0]) + 1.0f, A1 = EXP2F(p11[1]) + 1.0f;
            const float A2 = EXP2F(p11[2]) + 1.0f, A3 = EXP2F(p11[3]) + 1.0f;
            const float q01 = A0 * A1, q23 = A2 * A3;
            R11 = fmaf(fmaf(q01, A2 + A3, q23 * (A0 + A1)), RCPF(q01 * q23), R11);
        }
    }

    // reduce sigma-sums over quads
    R00 += __shfl_xor(R00, 16, 64);  R00 += __shfl_xor(R00, 32, 64);
    R01 += __shfl_xor(R01, 16, 64);  R01 += __shfl_xor(R01, 32, 64);
    R10 += __shfl_xor(R10, 16, 64);  R10 += __shfl_xor(R10, 32, 64);
    R11 += __shfl_xor(R11, 16, 64);  R11 += __shfl_xor(R11, 32, 64);

    // folded top-MLP coefficient u[o] (W2: s_loads; W1: divergent, L1-hot)
    float uo[2];
    #pragma unroll
    for (int nt = 0; nt < 2; ++nt) {
        const int o = nt * 16 + c16;
        const bool valid = (o < Ee);
        const int oc = valid ? o : 0;
        float s = 0.0f;
        #pragma unroll
        for (int p = 0; p < 10; ++p)
            s = fmaf(W2[p], W1[p * Ee + oc], s);
        uo[nt] = valid ? s : 0.0f;
    }

    // epilogue both rows: th = tanh(cf + m*agg); e = sum_o u[o]*th[o]
    float e = 0.0f;
    e = fmaf(tanhfast(cf0[0] + m0 * (256.0f - 2.0f * R00)), uo[0], e);
    e = fmaf(tanhfast(cf0[1] + m0 * (256.0f - 2.0f * R01)), uo[1], e);
    e = fmaf(tanhfast(cf1[0] + m1 * (256.0f - 2.0f * R10)), uo[0], e);
    e = fmaf(tanhfast(cf1[1] + m1 * (256.0f - 2.0f * R11)), uo[1], e);
    e += __shfl_xor(e, 1, 64);
    e += __shfl_xor(e, 2, 64);
    e += __shfl_xor(e, 4, 64);
    e += __shfl_xor(e, 8, 64);

    // block reduce: 4 waves -> one plain store (NO atomics)
    __shared__ float sE[4];
    if (lane == 0) sE[wave] = e;
    __syncthreads();
    if (tid == 0)
        part[blk] = sE[0] + sE[1] + sE[2] + sE[3];
}

// 64 blocks x 64 lanes: out[b] = sum of 32 block-partials + 256*C0
__global__ __launch_bounds__(64) void dtnn_reduce(
    const float* __restrict__ part,
    const float* __restrict__ b1, const float* __restrict__ W2,
    const float* __restrict__ b2, float* __restrict__ out)
{
    const int b = blockIdx.x;
    const int t = threadIdx.x;
    float v = (t < 32) ? part[b * 32 + t] : 0.0f;
    v += __shfl_xor(v, 1, 64);
    v += __shfl_xor(v, 2, 64);
    v += __shfl_xor(v, 4, 64);
    v += __shfl_xor(v, 8, 64);
    v += __shfl_xor(v, 16, 64);
    if (t == 0) {
        float c0 = b2[0];
        #pragma unroll
        for (int p = 0; p < 10; ++p) c0 = fmaf(W2[p], b1[p], c0);
        out[b] = v + __shfl(v, 32, 64) * 0.0f + 256.0f * c0 + __shfl_xor(v, 32, 64);
    }
}

extern "C" void kernel_launch(void* const* d_in, const int* in_sizes, int n_in,
                              void* d_out, int out_size, void* d_ws, size_t ws_size,
                              hipStream_t stream) {
    const int*   z    = (const int*)  d_in[0];
    const float* dist = (const float*)d_in[1];
    const float* emb  = (const float*)d_in[2];
    const float* Vw   = (const float*)d_in[3];
    const float* Vb   = (const float*)d_in[4];
    const float* W1   = (const float*)d_in[5];
    const float* b1   = (const float*)d_in[6];
    const float* W2   = (const float*)d_in[7];
    const float* b2   = (const float*)d_in[8];
    float* out = (float*)d_out;

    float* partP = (float*)d_ws;   // [NBLK]

    // 2 dispatches: fat main (2 rows/wave, self-contained) + tiny reduce
    dtnn_main<<<NBLK, 256, 0, stream>>>(z, dist, emb, Vw, Vb, W1, W2, partP);
    dtnn_reduce<<<Bsz, 64, 0, stream>>>(partP, b1, W2, b2, out);
}